// Round 1
// baseline (50.662 us; speedup 1.0000x reference)
//
#include <hip/hip_runtime.h>

// out[n,m] = -sum_d |x[n,d] - y[m,d]|   N=M=2048, D=128, fp32.
// VALU-bound: 2 ops/element (v_sub + v_add with abs modifier).
// 128x128 tile / block(256), 8x8 acc per thread, D chunked by 32 via LDS.
// XOR swizzle (16B granule) on LDS rows -> conflict-free ds_read_b128.

#define BM 128
#define BN 128
#define DK 32   // d-chunk in floats
#define TM 8
#define TN 8

__launch_bounds__(256)
__global__ void l1_dist_kernel(const float* __restrict__ X,
                               const float* __restrict__ Y,
                               float* __restrict__ out,
                               int N, int M, int D) {
    __shared__ float xs[BM * DK];
    __shared__ float ys[BN * DK];

    const int tx = threadIdx.x & 15;   // col group 0..15
    const int ty = threadIdx.x >> 4;   // row group 0..15
    const int brow = blockIdx.y * BM;
    const int bcol = blockIdx.x * BN;

    float acc[TM][TN];
#pragma unroll
    for (int i = 0; i < TM; ++i)
#pragma unroll
        for (int j = 0; j < TN; ++j) acc[i][j] = 0.f;

    for (int d0 = 0; d0 < D; d0 += DK) {
        __syncthreads();
        // Stage x-tile [BM][DK] and y-tile [BN][DK] into LDS.
        // BM*DK/4 = 1024 float4 per tile; 256 threads -> 4 each.
#pragma unroll
        for (int li = 0; li < (BM * DK / 4) / 256; ++li) {
            int idx = threadIdx.x + li * 256;
            int r = idx >> 3;      // row 0..127
            int q = idx & 7;       // 16B quad 0..7 within the 32-float chunk
            int sq = (q ^ (r & 7)) & 7;  // XOR swizzle at 16B granularity
            float4 v = *(const float4*)&X[(size_t)(brow + r) * D + d0 + (q << 2)];
            *(float4*)&xs[r * DK + (sq << 2)] = v;
            float4 w = *(const float4*)&Y[(size_t)(bcol + r) * D + d0 + (q << 2)];
            *(float4*)&ys[r * DK + (sq << 2)] = w;
        }
        __syncthreads();

        for (int dq = 0; dq < DK / 4; ++dq) {
            float4 xv[TM], yv[TN];
#pragma unroll
            for (int i = 0; i < TM; ++i) {
                int r = ty + 16 * i;
                xv[i] = *(const float4*)&xs[r * DK + ((((dq ^ r) & 7)) << 2)];
            }
#pragma unroll
            for (int j = 0; j < TN; ++j) {
                int c = tx + 16 * j;
                yv[j] = *(const float4*)&ys[c * DK + ((((dq ^ c) & 7)) << 2)];
            }
#pragma unroll
            for (int i = 0; i < TM; ++i)
#pragma unroll
                for (int j = 0; j < TN; ++j) {
                    acc[i][j] += __builtin_fabsf(xv[i].x - yv[j].x);
                    acc[i][j] += __builtin_fabsf(xv[i].y - yv[j].y);
                    acc[i][j] += __builtin_fabsf(xv[i].z - yv[j].z);
                    acc[i][j] += __builtin_fabsf(xv[i].w - yv[j].w);
                }
        }
    }

    // Epilogue: negate and store. Strided ownership -> 64B segments/wave.
#pragma unroll
    for (int i = 0; i < TM; ++i) {
        int r = brow + ty + 16 * i;
#pragma unroll
        for (int j = 0; j < TN; ++j) {
            int c = bcol + tx + 16 * j;
            out[(size_t)r * M + c] = -acc[i][j];
        }
    }
}

extern "C" void kernel_launch(void* const* d_in, const int* in_sizes, int n_in,
                              void* d_out, int out_size, void* d_ws, size_t ws_size,
                              hipStream_t stream) {
    const float* x = (const float*)d_in[0];
    const float* y = (const float*)d_in[1];
    float* out = (float*)d_out;
    const int D = 128;
    const int N = in_sizes[0] / D;
    const int M = in_sizes[1] / D;
    dim3 grid(M / BN, N / BM);
    l1_dist_kernel<<<grid, 256, 0, stream>>>(x, y, out, N, M, D);
}